// Round 1
// baseline (1487.772 us; speedup 1.0000x reference)
//
#include <hip/hip_runtime.h>
#include <hip/hip_bf16.h>

// Problem constants
#define BATCH 32
#define NSEQ  16384
#define DDIM  65
#define CHUNK 64
#define KQ    64
#define NBLK  256          // NSEQ / CHUNK
#define SCALE 0.12403473458920847f   // 65^-0.5

__device__ __forceinline__ float gelu_exact(float v) {
    return 0.5f * v * (1.0f + erff(v * 0.7071067811865476f));
}

// ---------------------------------------------------------------------------
// Kernel 1: global average over N.  grid (64 slices, 32 batch), 256 threads.
// Accumulates into gavg_ws[b*65+d] via atomicAdd (region pre-zeroed).
// ---------------------------------------------------------------------------
__global__ __launch_bounds__(256) void k_gavg(const float* __restrict__ x,
                                              float* __restrict__ gavg) {
    const int s = blockIdx.x;          // slice 0..63 (256 rows each)
    const int b = blockIdx.y;
    const int tid = threadIdx.x;
    const int w = tid >> 6, lane = tid & 63;
    const float* xb = x + (size_t)b * NSEQ * DDIM;
    const int n0 = s * 256;
    float acc = 0.f, acce = 0.f;
    for (int i = 0; i < 64; ++i) {
        const float* row = xb + (size_t)(n0 + w + i * 4) * DDIM;
        acc  += row[lane];      // d = lane (0..63), coalesced 256B
        acce += row[64];        // d = 64, broadcast load
    }
    __shared__ float part[4][DDIM];
    part[w][lane] = acc;
    if (lane == 0) part[w][64] = acce;
    __syncthreads();
    if (tid < DDIM) {
        float v = part[0][tid] + part[1][tid] + part[2][tid] + part[3][tid];
        atomicAdd(&gavg[b * DDIM + tid], v);
    }
}

// ---------------------------------------------------------------------------
// Kernel 2: q = (gelu(gavg@Wq1+bq1)@Wq2+bq2)*SCALE  and  r = gavg@Wr+br.
// grid 32 (one per b), 256 threads.  Tiny.
// ---------------------------------------------------------------------------
__global__ __launch_bounds__(256) void k_qgen(const float* __restrict__ gavg_in,
    const float* __restrict__ Wq1, const float* __restrict__ bq1,
    const float* __restrict__ Wq2, const float* __restrict__ bq2,
    const float* __restrict__ Wr,  const float* __restrict__ br,
    float* __restrict__ q_out, float* __restrict__ r_out) {
    const int b = blockIdx.x, tid = threadIdx.x;
    __shared__ float g[DDIM], h[DDIM];
    if (tid < DDIM) g[tid] = gavg_in[b * DDIM + tid] * (1.0f / 16384.0f);
    __syncthreads();
    if (tid < DDIM) {
        float a = bq1[tid];
        for (int e = 0; e < DDIM; ++e) a += g[e] * Wq1[e * DDIM + tid];
        h[tid] = gelu_exact(a);
    } else if (tid >= 128 && tid < 128 + DDIM) {
        const int d = tid - 128;
        float a = br[d];
        for (int e = 0; e < DDIM; ++e) a += g[e] * Wr[e * DDIM + d];
        r_out[b * DDIM + d] = a;
    }
    __syncthreads();
    for (int o = tid; o < KQ * DDIM; o += 256) {
        float a = bq2[o];
        for (int e = 0; e < DDIM; ++e) a += h[e] * Wq2[e * (KQ * DDIM) + o];
        q_out[(size_t)b * (KQ * DDIM) + o] = a * SCALE;
    }
}

// ---------------------------------------------------------------------------
// Kernel 3: per (b, chunk): keys/values (Linear+GELU+pos), scores, softmax,
// blk, and per-chunk cross-scores cs.  grid (256, 32), 256 threads.
// LDS: 67840 B -> 2 blocks/CU.
// ---------------------------------------------------------------------------
__global__ __launch_bounds__(256) void k_attn(const float* __restrict__ x,
    const float* __restrict__ q,
    const float* __restrict__ Wk, const float* __restrict__ bk,
    const float* __restrict__ Wv, const float* __restrict__ bv,
    const float* __restrict__ pos, const float* __restrict__ cq,
    __hip_bfloat16* __restrict__ blk_out, float* __restrict__ cs_out) {
    const int nb = blockIdx.x;     // chunk index 0..255
    const int b  = blockIdx.y;
    const int tid = threadIdx.x;

    __shared__ float xs[CHUNK * DDIM];          // x chunk, later reused as scr
    __shared__ float keys[CHUNK * 67];          // pad 67: conflict-free strides
    __shared__ float vals[CHUNK * 67];
    __shared__ float qs[KQ * DDIM];
    __shared__ float cs_l[KQ];

    const float* xsrc = x + ((size_t)b * NSEQ + (size_t)nb * CHUNK) * DDIM;
    for (int i = tid; i < CHUNK * DDIM; i += 256) xs[i] = xsrc[i];
    const float* qsrc = q + (size_t)b * (KQ * DDIM);
    for (int i = tid; i < KQ * DDIM; i += 256) qs[i] = qsrc[i];
    if (tid < KQ) cs_l[tid] = 0.f;
    __syncthreads();

    // ---- keys & values: 4x c-blocked (c0, c0+16, c0+32, c0+48) ----
    for (int idx = tid; idx < 16 * DDIM; idx += 256) {
        const int c0 = idx / DDIM;      // 0..15
        const int d  = idx % DDIM;
        const float bkd = bk[d], bvd = bv[d];
        float ak[4], av[4];
        #pragma unroll
        for (int j = 0; j < 4; ++j) { ak[j] = bkd; av[j] = bvd; }
        for (int e = 0; e < DDIM; ++e) {
            const float wk = Wk[e * DDIM + d];
            const float wv = Wv[e * DDIM + d];
            #pragma unroll
            for (int j = 0; j < 4; ++j) {
                const float xv = xs[(c0 + 16 * j) * DDIM + e];
                ak[j] += xv * wk;
                av[j] += xv * wv;
            }
        }
        #pragma unroll
        for (int j = 0; j < 4; ++j) {
            const int c = c0 + 16 * j;
            const float p = pos[c * DDIM + d];
            keys[c * 67 + d] = gelu_exact(ak[j]) + p;
            vals[c * 67 + d] = gelu_exact(av[j]) + p;
        }
    }
    __syncthreads();

    // ---- scores into scr (reuse of xs): 4x k-blocked ----
    float* scr = xs;
    for (int idx = tid; idx < 16 * CHUNK; idx += 256) {
        const int k0 = idx >> 6;        // 0..15
        const int c  = idx & 63;
        float a[4] = {0.f, 0.f, 0.f, 0.f};
        for (int d = 0; d < DDIM; ++d) {
            const float kv = keys[c * 67 + d];
            #pragma unroll
            for (int j = 0; j < 4; ++j)
                a[j] += qs[(k0 + 16 * j) * DDIM + d] * kv;
        }
        #pragma unroll
        for (int j = 0; j < 4; ++j)
            scr[(k0 + 16 * j) * DDIM + c] = a[j] * SCALE;
    }
    __syncthreads();

    // ---- softmax over c, per row k ----
    if (tid < KQ) {
        const int k = tid;
        float m = -1e30f;
        for (int c = 0; c < CHUNK; ++c) m = fmaxf(m, scr[k * DDIM + c]);
        float s = 0.f;
        for (int c = 0; c < CHUNK; ++c) {
            const float e = __expf(scr[k * DDIM + c] - m);
            scr[k * DDIM + c] = e;
            s += e;
        }
        const float inv = 1.0f / s;
        for (int c = 0; c < CHUNK; ++c) scr[k * DDIM + c] *= inv;
    }
    __syncthreads();

    // ---- blk = w @ values, bf16 store + cross-scores: 4x k-blocked ----
    for (int idx = tid; idx < 16 * DDIM; idx += 256) {
        const int k0 = idx / DDIM;      // 0..15
        const int d  = idx % DDIM;
        const float cqd = cq[d];
        float a[4] = {0.f, 0.f, 0.f, 0.f};
        for (int c = 0; c < CHUNK; ++c) {
            const float vv = vals[c * 67 + d];
            #pragma unroll
            for (int j = 0; j < 4; ++j)
                a[j] += scr[(k0 + 16 * j) * DDIM + c] * vv;
        }
        #pragma unroll
        for (int j = 0; j < 4; ++j) {
            const int k = k0 + 16 * j;
            blk_out[(((size_t)b * KQ + k) * NBLK + nb) * DDIM + d] =
                __float2bfloat16(a[j]);
            atomicAdd(&cs_l[k], a[j] * cqd);
        }
    }
    __syncthreads();
    if (tid < KQ)
        cs_out[((size_t)b * KQ + tid) * NBLK + nb] = cs_l[tid] * SCALE;
}

// ---------------------------------------------------------------------------
// Kernel 4: cross softmax over nb, weighted sum of blk, residual, LayerNorm.
// grid 2048 (= B*K), 256 threads.
// ---------------------------------------------------------------------------
__global__ __launch_bounds__(256) void k_cross(
    const __hip_bfloat16* __restrict__ blk, const float* __restrict__ cs,
    const float* __restrict__ r, const float* __restrict__ gamma,
    const float* __restrict__ beta, float* __restrict__ out) {
    const int bk_ = blockIdx.x;            // b*64 + k
    const int b = bk_ >> 6;
    const int tid = threadIdx.x;
    const int w = tid >> 6, lane = tid & 63;

    __shared__ float ew[NBLK];
    __shared__ float red[4][DDIM];
    __shared__ float vv[DDIM];
    __shared__ float wredA[4];
    __shared__ float stats[2];

    const float v = cs[(size_t)bk_ * NBLK + tid];
    // block max
    float m = v;
    for (int off = 32; off; off >>= 1) m = fmaxf(m, __shfl_down(m, off));
    if (lane == 0) wredA[w] = m;
    __syncthreads();
    m = fmaxf(fmaxf(wredA[0], wredA[1]), fmaxf(wredA[2], wredA[3]));
    const float e = __expf(v - m);
    ew[tid] = e;
    float s = e;
    for (int off = 32; off; off >>= 1) s += __shfl_down(s, off);
    __syncthreads();                       // wredA reads done, ew visible
    if (lane == 0) wredA[w] = s;
    __syncthreads();
    const float inv = 1.0f / (wredA[0] + wredA[1] + wredA[2] + wredA[3]);

    // weighted sum over 256 chunks; lane covers d=lane, plus shared d=64
    const __hip_bfloat16* base = blk + (size_t)bk_ * NBLK * DDIM;
    float acc = 0.f, acce = 0.f;
    for (int i = 0; i < 64; ++i) {
        const int n = w + i * 4;
        const __hip_bfloat16* row = base + n * DDIM;
        const float wgt = ew[n];
        acc  += wgt * __bfloat162float(row[lane]);
        acce += wgt * __bfloat162float(row[64]);
    }
    red[w][lane] = acc;
    if (lane == 0) red[w][64] = acce;
    __syncthreads();
    if (tid < DDIM) {
        vv[tid] = (red[0][tid] + red[1][tid] + red[2][tid] + red[3][tid]) * inv
                  + r[b * DDIM + tid];
    }
    __syncthreads();
    // LayerNorm stats via wave 0
    if (tid < 64) {
        float a  = vv[tid] + (tid == 0 ? vv[64] : 0.f);
        float sq = vv[tid] * vv[tid] + (tid == 0 ? vv[64] * vv[64] : 0.f);
        for (int off = 32; off; off >>= 1) {
            a  += __shfl_down(a, off);
            sq += __shfl_down(sq, off);
        }
        if (tid == 0) {
            const float mu  = a * (1.0f / DDIM);
            const float var = sq * (1.0f / DDIM) - mu * mu;
            stats[0] = mu;
            stats[1] = rsqrtf(var + 1e-5f);
        }
    }
    __syncthreads();
    if (tid < DDIM) {
        out[(size_t)bk_ * DDIM + tid] =
            (vv[tid] - stats[0]) * stats[1] * gamma[tid] + beta[tid];
    }
}

// ---------------------------------------------------------------------------
extern "C" void kernel_launch(void* const* d_in, const int* in_sizes, int n_in,
                              void* d_out, int out_size, void* d_ws, size_t ws_size,
                              hipStream_t stream) {
    const float* x    = (const float*)d_in[0];
    const float* Wq1  = (const float*)d_in[1];
    const float* bq1  = (const float*)d_in[2];
    const float* Wq2  = (const float*)d_in[3];
    const float* bq2  = (const float*)d_in[4];
    const float* Wk   = (const float*)d_in[5];
    const float* bk   = (const float*)d_in[6];
    const float* Wv   = (const float*)d_in[7];
    const float* bv   = (const float*)d_in[8];
    const float* cq   = (const float*)d_in[9];
    const float* pos  = (const float*)d_in[10];
    const float* Wr   = (const float*)d_in[11];
    const float* br   = (const float*)d_in[12];
    const float* gamma= (const float*)d_in[13];
    const float* beta = (const float*)d_in[14];
    float* out = (float*)d_out;

    // workspace layout (floats)
    float* ws   = (float*)d_ws;
    float* gavg = ws;                       // 2080
    float* r    = ws + 2080;                // 2080
    float* q    = ws + 4160;                // 133120
    float* cs   = ws + 137280;              // 524288
    __hip_bfloat16* blk = (__hip_bfloat16*)(ws + 661568);  // 34078720 bf16

    hipMemsetAsync(gavg, 0, 2080 * sizeof(float), stream);
    k_gavg<<<dim3(64, BATCH), 256, 0, stream>>>(x, gavg);
    k_qgen<<<BATCH, 256, 0, stream>>>(gavg, Wq1, bq1, Wq2, bq2, Wr, br, q, r);
    k_attn<<<dim3(NBLK, BATCH), 256, 0, stream>>>(x, q, Wk, bk, Wv, bv, pos, cq,
                                                  blk, cs);
    k_cross<<<BATCH * KQ, 256, 0, stream>>>(blk, cs, r, gamma, beta, out);
}

// Round 2
// 795.522 us; speedup vs baseline: 1.8702x; 1.8702x over previous
//
#include <hip/hip_runtime.h>
#include <hip/hip_bf16.h>

// Problem constants
#define BATCH 32
#define NSEQ  16384
#define DDIM  65
#define CHUNK 64
#define KQ    64
#define NBLK  256          // NSEQ / CHUNK
#define SCALE 0.12403473458920847f   // 65^-0.5

typedef __bf16 bf16x8 __attribute__((ext_vector_type(8)));
typedef float  f32x4  __attribute__((ext_vector_type(4)));
#define MFMA16(a, b, c) __builtin_amdgcn_mfma_f32_16x16x32_bf16(a, b, c, 0, 0, 0)

__device__ __forceinline__ float gelu_exact(float v) {
    return 0.5f * v * (1.0f + erff(v * 0.7071067811865476f));
}

// ---------------------------------------------------------------------------
// Kernel 0: transpose+pad Wk,Wv to bf16 WT[80][64]: WT[d][e] = W[e][d], rows
// 65..79 zero.  One-shot tiny kernel.
// ---------------------------------------------------------------------------
__global__ __launch_bounds__(256) void k_prep(const float* __restrict__ Wk,
                                              const float* __restrict__ Wv,
                                              __bf16* __restrict__ WkT,
                                              __bf16* __restrict__ WvT) {
    int i = blockIdx.x * 256 + threadIdx.x;     // 0 .. 2*80*64-1
    if (i >= 2 * 80 * 64) return;
    int m = i / 5120;
    int j = i - m * 5120;
    int d = j >> 6, e = j & 63;
    const float* W = m ? Wv : Wk;
    __bf16* T = m ? WvT : WkT;
    T[(size_t)d * 64 + e] = (d < DDIM) ? (__bf16)W[e * DDIM + d] : (__bf16)0.0f;
}

// ---------------------------------------------------------------------------
// Kernel 1: global average over N.  grid (64 slices, 32 batch), 256 threads.
// ---------------------------------------------------------------------------
__global__ __launch_bounds__(256) void k_gavg(const float* __restrict__ x,
                                              float* __restrict__ gavg) {
    const int s = blockIdx.x;
    const int b = blockIdx.y;
    const int tid = threadIdx.x;
    const int w = tid >> 6, lane = tid & 63;
    const float* xb = x + (size_t)b * NSEQ * DDIM;
    const int n0 = s * 256;
    float acc = 0.f, acce = 0.f;
    for (int i = 0; i < 64; ++i) {
        const float* row = xb + (size_t)(n0 + w + i * 4) * DDIM;
        acc  += row[lane];
        acce += row[64];
    }
    __shared__ float part[4][DDIM];
    part[w][lane] = acc;
    if (lane == 0) part[w][64] = acce;
    __syncthreads();
    if (tid < DDIM) {
        float v = part[0][tid] + part[1][tid] + part[2][tid] + part[3][tid];
        atomicAdd(&gavg[b * DDIM + tid], v);
    }
}

// ---------------------------------------------------------------------------
// Kernel 2: q = (gelu(gavg@Wq1+bq1)@Wq2+bq2)*SCALE  (-> bf16 [64][64] + fp32
// col64) and r = gavg@Wr+br.  grid 32.
// ---------------------------------------------------------------------------
__global__ __launch_bounds__(256) void k_qgen(const float* __restrict__ gavg_in,
    const float* __restrict__ Wq1, const float* __restrict__ bq1,
    const float* __restrict__ Wq2, const float* __restrict__ bq2,
    const float* __restrict__ Wr,  const float* __restrict__ br,
    __bf16* __restrict__ qbf, float* __restrict__ q64,
    float* __restrict__ r_out) {
    const int b = blockIdx.x, tid = threadIdx.x;
    __shared__ float g[DDIM], h[DDIM];
    if (tid < DDIM) g[tid] = gavg_in[b * DDIM + tid] * (1.0f / 16384.0f);
    __syncthreads();
    if (tid < DDIM) {
        float a = bq1[tid];
        for (int e = 0; e < DDIM; ++e) a += g[e] * Wq1[e * DDIM + tid];
        h[tid] = gelu_exact(a);
    } else if (tid >= 128 && tid < 128 + DDIM) {
        const int d = tid - 128;
        float a = br[d];
        for (int e = 0; e < DDIM; ++e) a += g[e] * Wr[e * DDIM + d];
        r_out[b * DDIM + d] = a;
    }
    __syncthreads();
    for (int o = tid; o < KQ * DDIM; o += 256) {
        const int k = o / DDIM, d = o - k * DDIM;
        float a = bq2[o];
        for (int e = 0; e < DDIM; ++e) a += h[e] * Wq2[e * (KQ * DDIM) + o];
        a *= SCALE;
        if (d < 64) qbf[(size_t)b * 4096 + k * 64 + d] = (__bf16)a;
        else        q64[b * 64 + k] = a;
    }
}

// ---------------------------------------------------------------------------
// Kernel 3 (MFMA): per (b, chunk): keys/vals = gelu(X@W+b)+pos, S = q@keys^T,
// softmax, blk = P@vals, cs.  grid (256, 32), 256 thr (4 waves).
// LDS 38.7 KB -> 4 blocks/CU (16 waves).  D=65 split: MFMA over 64 + fp32
// rank-1 fixup; output col d=64 via zero-padded N tile (nt=4).
// ---------------------------------------------------------------------------
__global__ __launch_bounds__(256, 4) void k_attn(const float* __restrict__ x,
    const __bf16* __restrict__ qbf, const float* __restrict__ q64,
    const __bf16* __restrict__ WkT, const __bf16* __restrict__ WvT,
    const float* __restrict__ Wk, const float* __restrict__ bkb,
    const float* __restrict__ Wv, const float* __restrict__ bvb,
    const float* __restrict__ pos, const float* __restrict__ cq,
    __bf16* __restrict__ blk_out, float* __restrict__ cs_out) {
    const int nb = blockIdx.x;
    const int b  = blockIdx.y;
    const int tid = threadIdx.x;
    const int lane = tid & 63, w = tid >> 6;
    const int l16 = lane & 15, quad = lane >> 4;

    // region A: xs_bf (phase 1-2) -> S fp32 (phase 3) -> P bf16 (phase 4-5)
    __shared__ __align__(16) unsigned char regionA[64 * 68 * 4];
    __shared__ float xs64[64];
    __shared__ __align__(16) __bf16 keys[64 * 72];   // [c][d], d<=64 valid
    __shared__ __align__(16) __bf16 valsT[80 * 72];  // [d][c], d<=64 valid
    __shared__ float cs_l[64];
    __bf16* xs_bf = (__bf16*)regionA;   // [64][72]
    float*  S     = (float*)regionA;    // [64][68]
    __bf16* P     = (__bf16*)regionA;   // [64][72]

    // ---- phase 1: stage x chunk ----
    const float* xsrc = x + ((size_t)b * NSEQ + (size_t)nb * CHUNK) * DDIM;
    for (int i = tid; i < CHUNK * DDIM; i += 256) {
        int c = i / DDIM, e = i - c * DDIM;
        float v = xsrc[i];
        if (e < 64) xs_bf[c * 72 + e] = (__bf16)v;
        else        xs64[c] = v;
    }
    __syncthreads();

    // ---- phase 2: keys/vals via MFMA (M=c rows w*16.., N=d 5 tiles, K=64) --
    {
        const __bf16* arow = xs_bf + (w * 16 + l16) * 72 + quad * 8;
        bf16x8 a0 = *(const bf16x8*)arow;
        bf16x8 a1 = *(const bf16x8*)(arow + 32);
        f32x4 ak[5], av[5];
        const f32x4 z = {0.f, 0.f, 0.f, 0.f};
        #pragma unroll
        for (int nt = 0; nt < 5; ++nt) {
            const __bf16* bkr = WkT + (nt * 16 + l16) * 64 + quad * 8;
            const __bf16* bvr = WvT + (nt * 16 + l16) * 64 + quad * 8;
            ak[nt] = MFMA16(a0, *(const bf16x8*)bkr, z);
            ak[nt] = MFMA16(a1, *(const bf16x8*)(bkr + 32), ak[nt]);
            av[nt] = MFMA16(a0, *(const bf16x8*)bvr, z);
            av[nt] = MFMA16(a1, *(const bf16x8*)(bvr + 32), av[nt]);
        }
        #pragma unroll
        for (int nt = 0; nt < 5; ++nt) {
            const int d = nt * 16 + l16;
            if (d <= 64) {
                const float wk64d = Wk[64 * DDIM + d];
                const float wv64d = Wv[64 * DDIM + d];
                const float bkd = bkb[d], bvd = bvb[d];
                #pragma unroll
                for (int r = 0; r < 4; ++r) {
                    const int c = w * 16 + quad * 4 + r;
                    const float xe = xs64[c];
                    const float pv = pos[c * DDIM + d];
                    keys[c * 72 + d]  = (__bf16)(gelu_exact(ak[nt][r] + xe * wk64d + bkd) + pv);
                    valsT[d * 72 + c] = (__bf16)(gelu_exact(av[nt][r] + xe * wv64d + bvd) + pv);
                }
            }
        }
    }
    __syncthreads();

    // ---- phase 3: S = q @ keys^T (M=k, N=c, K=64) + rank-1 fixup ----
    {
        const __bf16* aq = qbf + (size_t)b * 4096 + (w * 16 + l16) * 64 + quad * 8;
        bf16x8 qa0 = *(const bf16x8*)aq;
        bf16x8 qa1 = *(const bf16x8*)(aq + 32);
        f32x4 sacc[4];
        const f32x4 z = {0.f, 0.f, 0.f, 0.f};
        #pragma unroll
        for (int nt = 0; nt < 4; ++nt) {
            const __bf16* kb = keys + (nt * 16 + l16) * 72 + quad * 8;
            sacc[nt] = MFMA16(qa0, *(const bf16x8*)kb, z);
            sacc[nt] = MFMA16(qa1, *(const bf16x8*)(kb + 32), sacc[nt]);
        }
        float q64k[4];
        #pragma unroll
        for (int r = 0; r < 4; ++r) q64k[r] = q64[b * 64 + w * 16 + quad * 4 + r];
        #pragma unroll
        for (int nt = 0; nt < 4; ++nt) {
            const int c = nt * 16 + l16;
            const float k64c = (float)keys[c * 72 + 64];
            #pragma unroll
            for (int r = 0; r < 4; ++r) {
                const int k = w * 16 + quad * 4 + r;
                S[k * 68 + c] = (sacc[nt][r] + q64k[r] * k64c) * SCALE;
            }
        }
    }
    __syncthreads();

    // ---- phase 4: softmax rows of S -> P (bf16) ----
    {
        const int row = tid >> 2, qtr = tid & 3;
        float v16[16];
        float m = -1e30f;
        #pragma unroll
        for (int i = 0; i < 16; ++i) {
            v16[i] = S[row * 68 + qtr * 16 + i];
            m = fmaxf(m, v16[i]);
        }
        m = fmaxf(m, __shfl_xor(m, 1));
        m = fmaxf(m, __shfl_xor(m, 2));
        float s = 0.f;
        #pragma unroll
        for (int i = 0; i < 16; ++i) { v16[i] = __expf(v16[i] - m); s += v16[i]; }
        s += __shfl_xor(s, 1);
        s += __shfl_xor(s, 2);
        const float inv = 1.0f / s;
        __syncthreads();                     // all S reads done before P overlay
        #pragma unroll
        for (int i = 0; i < 16; ++i)
            P[row * 72 + qtr * 16 + i] = (__bf16)(v16[i] * inv);
    }
    __syncthreads();

    // ---- phase 5: blk = P @ vals (M=k, N=d 5 tiles, K=c=64) + cs ----
    {
        const __bf16* pr = P + (w * 16 + l16) * 72 + quad * 8;
        bf16x8 pa0 = *(const bf16x8*)pr;
        bf16x8 pa1 = *(const bf16x8*)(pr + 32);
        const f32x4 z = {0.f, 0.f, 0.f, 0.f};
        float csr[4] = {0.f, 0.f, 0.f, 0.f};
        #pragma unroll
        for (int nt = 0; nt < 5; ++nt) {
            const __bf16* vb = valsT + (nt * 16 + l16) * 72 + quad * 8;
            f32x4 o = MFMA16(pa0, *(const bf16x8*)vb, z);
            o = MFMA16(pa1, *(const bf16x8*)(vb + 32), o);
            const int d = nt * 16 + l16;
            const bool valid = (d <= 64);
            const float cqd = valid ? cq[d] : 0.f;
            #pragma unroll
            for (int r = 0; r < 4; ++r) {
                const int k = w * 16 + quad * 4 + r;
                if (valid) {
                    blk_out[(((size_t)b * KQ + k) * NBLK + nb) * DDIM + d] =
                        (__bf16)o[r];
                    csr[r] += o[r] * cqd;     // guarded: no NaN from pad cols
                }
            }
        }
        #pragma unroll
        for (int r = 0; r < 4; ++r) {
            float v = csr[r];
            v += __shfl_xor(v, 1);
            v += __shfl_xor(v, 2);
            v += __shfl_xor(v, 4);
            v += __shfl_xor(v, 8);
            if (l16 == 0) cs_l[w * 16 + quad * 4 + r] = v;
        }
    }
    __syncthreads();
    if (tid < KQ)
        cs_out[((size_t)b * KQ + tid) * NBLK + nb] = cs_l[tid] * SCALE;
}

// ---------------------------------------------------------------------------
// Kernel 4: cross softmax over nb, weighted sum of blk, residual, LayerNorm.
// ---------------------------------------------------------------------------
__global__ __launch_bounds__(256) void k_cross(
    const __bf16* __restrict__ blk, const float* __restrict__ cs,
    const float* __restrict__ r, const float* __restrict__ gamma,
    const float* __restrict__ beta, float* __restrict__ out) {
    const int bk_ = blockIdx.x;
    const int b = bk_ >> 6;
    const int tid = threadIdx.x;
    const int w = tid >> 6, lane = tid & 63;

    __shared__ float ew[NBLK];
    __shared__ float red[4][DDIM];
    __shared__ float vv[DDIM];
    __shared__ float wredA[4];
    __shared__ float stats[2];

    const float v = cs[(size_t)bk_ * NBLK + tid];
    float m = v;
    for (int off = 32; off; off >>= 1) m = fmaxf(m, __shfl_down(m, off));
    if (lane == 0) wredA[w] = m;
    __syncthreads();
    m = fmaxf(fmaxf(wredA[0], wredA[1]), fmaxf(wredA[2], wredA[3]));
    const float e = __expf(v - m);
    ew[tid] = e;
    float s = e;
    for (int off = 32; off; off >>= 1) s += __shfl_down(s, off);
    __syncthreads();
    if (lane == 0) wredA[w] = s;
    __syncthreads();
    const float inv = 1.0f / (wredA[0] + wredA[1] + wredA[2] + wredA[3]);

    const __bf16* base = blk + (size_t)bk_ * NBLK * DDIM;
    float acc = 0.f, acce = 0.f;
    for (int i = 0; i < 64; ++i) {
        const int n = w + i * 4;
        const __bf16* row = base + n * DDIM;
        const float wgt = ew[n];
        acc  += wgt * (float)row[lane];
        acce += wgt * (float)row[64];
    }
    red[w][lane] = acc;
    if (lane == 0) red[w][64] = acce;
    __syncthreads();
    if (tid < DDIM) {
        vv[tid] = (red[0][tid] + red[1][tid] + red[2][tid] + red[3][tid]) * inv
                  + r[b * DDIM + tid];
    }
    __syncthreads();
    if (tid < 64) {
        float a  = vv[tid] + (tid == 0 ? vv[64] : 0.f);
        float sq = vv[tid] * vv[tid] + (tid == 0 ? vv[64] * vv[64] : 0.f);
        for (int off = 32; off; off >>= 1) {
            a  += __shfl_down(a, off);
            sq += __shfl_down(sq, off);
        }
        if (tid == 0) {
            const float mu  = a * (1.0f / DDIM);
            const float var = sq * (1.0f / DDIM) - mu * mu;
            stats[0] = mu;
            stats[1] = rsqrtf(var + 1e-5f);
        }
    }
    __syncthreads();
    if (tid < DDIM) {
        out[(size_t)bk_ * DDIM + tid] =
            (vv[tid] - stats[0]) * stats[1] * gamma[tid] + beta[tid];
    }
}

// ---------------------------------------------------------------------------
extern "C" void kernel_launch(void* const* d_in, const int* in_sizes, int n_in,
                              void* d_out, int out_size, void* d_ws, size_t ws_size,
                              hipStream_t stream) {
    const float* x    = (const float*)d_in[0];
    const float* Wq1  = (const float*)d_in[1];
    const float* bq1  = (const float*)d_in[2];
    const float* Wq2  = (const float*)d_in[3];
    const float* bq2  = (const float*)d_in[4];
    const float* Wk   = (const float*)d_in[5];
    const float* bk   = (const float*)d_in[6];
    const float* Wv   = (const float*)d_in[7];
    const float* bv   = (const float*)d_in[8];
    const float* cq   = (const float*)d_in[9];
    const float* pos  = (const float*)d_in[10];
    const float* Wr   = (const float*)d_in[11];
    const float* br   = (const float*)d_in[12];
    const float* gamma= (const float*)d_in[13];
    const float* beta = (const float*)d_in[14];
    float* out = (float*)d_out;

    // workspace layout (byte offsets, all 16B-aligned)
    char* w8 = (char*)d_ws;
    float*  gavg = (float*)w8;                       // 2080 f
    float*  rres = gavg + 2080;                      // 2080 f
    float*  q64  = rres + 2080;                      // 2048 f
    float*  cs   = q64 + 2048;                       // 524288 f
    __bf16* qbf  = (__bf16*)(w8 + 2121984);          // 131072 bf16
    __bf16* WkT  = (__bf16*)(w8 + 2384128);          // 5120 bf16
    __bf16* WvT  = (__bf16*)(w8 + 2394368);          // 5120 bf16
    __bf16* blk  = (__bf16*)(w8 + 2404608);          // 34078720 bf16

    hipMemsetAsync(gavg, 0, 2080 * sizeof(float), stream);
    k_prep<<<40, 256, 0, stream>>>(Wk, Wv, WkT, WvT);
    k_gavg<<<dim3(64, BATCH), 256, 0, stream>>>(x, gavg);
    k_qgen<<<BATCH, 256, 0, stream>>>(gavg, Wq1, bq1, Wq2, bq2, Wr, br,
                                      qbf, q64, rres);
    k_attn<<<dim3(NBLK, BATCH), 256, 0, stream>>>(x, qbf, q64, WkT, WvT,
                                                  Wk, bk, Wv, bv, pos, cq,
                                                  blk, cs);
    k_cross<<<BATCH * KQ, 256, 0, stream>>>(blk, cs, rres, gamma, beta, out);
}

// Round 3
// 438.644 us; speedup vs baseline: 3.3918x; 1.8136x over previous
//
#include <hip/hip_runtime.h>
#include <hip/hip_bf16.h>

// Problem constants
#define BATCH 32
#define NSEQ  16384
#define DDIM  65
#define CHUNK 64
#define KQ    64
#define NBLK  256          // NSEQ / CHUNK
#define SCALE 0.12403473458920847f   // 65^-0.5

typedef __bf16 bf16x8 __attribute__((ext_vector_type(8)));
typedef float  f32x4  __attribute__((ext_vector_type(4)));
#define MFMA16(a, b, c) __builtin_amdgcn_mfma_f32_16x16x32_bf16(a, b, c, 0, 0, 0)

__device__ __forceinline__ float gelu_exact(float v) {
    return 0.5f * v * (1.0f + erff(v * 0.7071067811865476f));
}

// ---------------------------------------------------------------------------
// Kernel 0: transpose+pad Wk,Wv to bf16 WT[80][64]: WT[d][e] = W[e][d], rows
// 65..79 zero.  One-shot tiny kernel.
// ---------------------------------------------------------------------------
__global__ __launch_bounds__(256) void k_prep(const float* __restrict__ Wk,
                                              const float* __restrict__ Wv,
                                              __bf16* __restrict__ WkT,
                                              __bf16* __restrict__ WvT) {
    int i = blockIdx.x * 256 + threadIdx.x;     // 0 .. 2*80*64-1
    if (i >= 2 * 80 * 64) return;
    int m = i / 5120;
    int j = i - m * 5120;
    int d = j >> 6, e = j & 63;
    const float* W = m ? Wv : Wk;
    __bf16* T = m ? WvT : WkT;
    T[(size_t)d * 64 + e] = (d < DDIM) ? (__bf16)W[e * DDIM + d] : (__bf16)0.0f;
}

// ---------------------------------------------------------------------------
// Kernel 1: global average over N.  grid (64 slices, 32 batch), 256 threads.
// ---------------------------------------------------------------------------
__global__ __launch_bounds__(256) void k_gavg(const float* __restrict__ x,
                                              float* __restrict__ gavg) {
    const int s = blockIdx.x;
    const int b = blockIdx.y;
    const int tid = threadIdx.x;
    const int w = tid >> 6, lane = tid & 63;
    const float* xb = x + (size_t)b * NSEQ * DDIM;
    const int n0 = s * 256;
    float acc = 0.f, acce = 0.f;
    for (int i = 0; i < 64; ++i) {
        const float* row = xb + (size_t)(n0 + w + i * 4) * DDIM;
        acc  += row[lane];
        acce += row[64];
    }
    __shared__ float part[4][DDIM];
    part[w][lane] = acc;
    if (lane == 0) part[w][64] = acce;
    __syncthreads();
    if (tid < DDIM) {
        float v = part[0][tid] + part[1][tid] + part[2][tid] + part[3][tid];
        atomicAdd(&gavg[b * DDIM + tid], v);
    }
}

// ---------------------------------------------------------------------------
// Kernel 2a: h = gelu(gavg@Wq1+bq1), r = gavg@Wr+br.  grid 32, tiny.
// ---------------------------------------------------------------------------
__global__ __launch_bounds__(256) void k_qgen1(const float* __restrict__ gavg_in,
    const float* __restrict__ Wq1, const float* __restrict__ bq1,
    const float* __restrict__ Wr,  const float* __restrict__ br,
    float* __restrict__ h_out, float* __restrict__ r_out) {
    const int b = blockIdx.x, tid = threadIdx.x;
    __shared__ float g[DDIM];
    if (tid < DDIM) g[tid] = gavg_in[b * DDIM + tid] * (1.0f / 16384.0f);
    __syncthreads();
    if (tid < DDIM) {
        float a = bq1[tid];
        for (int e = 0; e < DDIM; ++e) a += g[e] * Wq1[e * DDIM + tid];
        h_out[b * DDIM + tid] = gelu_exact(a);
    } else if (tid >= 128 && tid < 128 + DDIM) {
        const int d = tid - 128;
        float a = br[d];
        for (int e = 0; e < DDIM; ++e) a += g[e] * Wr[e * DDIM + d];
        r_out[b * DDIM + d] = a;
    }
}

// ---------------------------------------------------------------------------
// Kernel 2b: q = (h@Wq2+bq2)*SCALE -> qbf [64][64] bf16 + q64 col.  grid
// (17 o-tiles, 32 b), one output/thread, coalesced Wq2 columns.
// ---------------------------------------------------------------------------
__global__ __launch_bounds__(256) void k_qgen2(const float* __restrict__ h_in,
    const float* __restrict__ Wq2, const float* __restrict__ bq2,
    __bf16* __restrict__ qbf, float* __restrict__ q64) {
    const int b = blockIdx.y, tid = threadIdx.x;
    const int o = blockIdx.x * 256 + tid;
    __shared__ float h[DDIM];
    if (tid < DDIM) h[tid] = h_in[b * DDIM + tid];
    __syncthreads();
    if (o >= KQ * DDIM) return;
    float a = bq2[o];
    #pragma unroll 13
    for (int e = 0; e < DDIM; ++e) a += h[e] * Wq2[e * (KQ * DDIM) + o];
    a *= SCALE;
    const int k = o / DDIM, d = o - k * DDIM;
    if (d < 64) qbf[(size_t)b * 4096 + k * 64 + d] = (__bf16)a;
    else        q64[b * 64 + k] = a;
}

// ---------------------------------------------------------------------------
// Kernel 3 (MFMA): per (b, chunk): keys/vals = gelu(X@W+b)+pos, S = q@keys^T,
// softmax, blk = P@vals, cs.  grid (256, 32), 256 thr (4 waves).
// LDS 38.7 KB -> 4 blocks/CU (16 waves).  D=65 split: MFMA over 64 + fp32
// rank-1 fixup; output col d=64 via zero-padded N tile (nt=4).
// ---------------------------------------------------------------------------
__global__ __launch_bounds__(256, 4) void k_attn(const float* __restrict__ x,
    const __bf16* __restrict__ qbf, const float* __restrict__ q64,
    const __bf16* __restrict__ WkT, const __bf16* __restrict__ WvT,
    const float* __restrict__ Wk, const float* __restrict__ bkb,
    const float* __restrict__ Wv, const float* __restrict__ bvb,
    const float* __restrict__ pos, const float* __restrict__ cq,
    __bf16* __restrict__ blk_out, float* __restrict__ cs_out) {
    const int nb = blockIdx.x;
    const int b  = blockIdx.y;
    const int tid = threadIdx.x;
    const int lane = tid & 63, w = tid >> 6;
    const int l16 = lane & 15, quad = lane >> 4;

    // region A: xs_bf (phase 1-2) -> S fp32 (phase 3) -> P bf16 (phase 4-5)
    __shared__ __align__(16) unsigned char regionA[64 * 68 * 4];
    __shared__ float xs64[64];
    __shared__ __align__(16) __bf16 keys[64 * 72];   // [c][d], d<=64 valid
    __shared__ __align__(16) __bf16 valsT[80 * 72];  // [d][c], d<=64 valid
    __shared__ float cs_l[64];
    __bf16* xs_bf = (__bf16*)regionA;   // [64][72]
    float*  S     = (float*)regionA;    // [64][68]
    __bf16* P     = (__bf16*)regionA;   // [64][72]

    // ---- phase 1: stage x chunk ----
    const float* xsrc = x + ((size_t)b * NSEQ + (size_t)nb * CHUNK) * DDIM;
    for (int i = tid; i < CHUNK * DDIM; i += 256) {
        int c = i / DDIM, e = i - c * DDIM;
        float v = xsrc[i];
        if (e < 64) xs_bf[c * 72 + e] = (__bf16)v;
        else        xs64[c] = v;
    }
    __syncthreads();

    // ---- phase 2: keys/vals via MFMA (M=c rows w*16.., N=d 5 tiles, K=64) --
    {
        const __bf16* arow = xs_bf + (w * 16 + l16) * 72 + quad * 8;
        bf16x8 a0 = *(const bf16x8*)arow;
        bf16x8 a1 = *(const bf16x8*)(arow + 32);
        f32x4 ak[5], av[5];
        const f32x4 z = {0.f, 0.f, 0.f, 0.f};
        #pragma unroll
        for (int nt = 0; nt < 5; ++nt) {
            const __bf16* bkr = WkT + (nt * 16 + l16) * 64 + quad * 8;
            const __bf16* bvr = WvT + (nt * 16 + l16) * 64 + quad * 8;
            ak[nt] = MFMA16(a0, *(const bf16x8*)bkr, z);
            ak[nt] = MFMA16(a1, *(const bf16x8*)(bkr + 32), ak[nt]);
            av[nt] = MFMA16(a0, *(const bf16x8*)bvr, z);
            av[nt] = MFMA16(a1, *(const bf16x8*)(bvr + 32), av[nt]);
        }
        #pragma unroll
        for (int nt = 0; nt < 5; ++nt) {
            const int d = nt * 16 + l16;
            if (d <= 64) {
                const float wk64d = Wk[64 * DDIM + d];
                const float wv64d = Wv[64 * DDIM + d];
                const float bkd = bkb[d], bvd = bvb[d];
                #pragma unroll
                for (int r = 0; r < 4; ++r) {
                    const int c = w * 16 + quad * 4 + r;
                    const float xe = xs64[c];
                    const float pv = pos[c * DDIM + d];
                    keys[c * 72 + d]  = (__bf16)(gelu_exact(ak[nt][r] + xe * wk64d + bkd) + pv);
                    valsT[d * 72 + c] = (__bf16)(gelu_exact(av[nt][r] + xe * wv64d + bvd) + pv);
                }
            }
        }
    }
    __syncthreads();

    // ---- phase 3: S = q @ keys^T (M=k, N=c, K=64) + rank-1 fixup ----
    {
        const __bf16* aq = qbf + (size_t)b * 4096 + (w * 16 + l16) * 64 + quad * 8;
        bf16x8 qa0 = *(const bf16x8*)aq;
        bf16x8 qa1 = *(const bf16x8*)(aq + 32);
        f32x4 sacc[4];
        const f32x4 z = {0.f, 0.f, 0.f, 0.f};
        #pragma unroll
        for (int nt = 0; nt < 4; ++nt) {
            const __bf16* kb = keys + (nt * 16 + l16) * 72 + quad * 8;
            sacc[nt] = MFMA16(qa0, *(const bf16x8*)kb, z);
            sacc[nt] = MFMA16(qa1, *(const bf16x8*)(kb + 32), sacc[nt]);
        }
        float q64k[4];
        #pragma unroll
        for (int r = 0; r < 4; ++r) q64k[r] = q64[b * 64 + w * 16 + quad * 4 + r];
        #pragma unroll
        for (int nt = 0; nt < 4; ++nt) {
            const int c = nt * 16 + l16;
            const float k64c = (float)keys[c * 72 + 64];
            #pragma unroll
            for (int r = 0; r < 4; ++r) {
                const int k = w * 16 + quad * 4 + r;
                S[k * 68 + c] = (sacc[nt][r] + q64k[r] * k64c) * SCALE;
            }
        }
    }
    __syncthreads();

    // ---- phase 4: softmax rows of S -> P (bf16) ----
    {
        const int row = tid >> 2, qtr = tid & 3;
        float v16[16];
        float m = -1e30f;
        #pragma unroll
        for (int i = 0; i < 16; ++i) {
            v16[i] = S[row * 68 + qtr * 16 + i];
            m = fmaxf(m, v16[i]);
        }
        m = fmaxf(m, __shfl_xor(m, 1));
        m = fmaxf(m, __shfl_xor(m, 2));
        float s = 0.f;
        #pragma unroll
        for (int i = 0; i < 16; ++i) { v16[i] = __expf(v16[i] - m); s += v16[i]; }
        s += __shfl_xor(s, 1);
        s += __shfl_xor(s, 2);
        const float inv = 1.0f / s;
        __syncthreads();                     // all S reads done before P overlay
        #pragma unroll
        for (int i = 0; i < 16; ++i)
            P[row * 72 + qtr * 16 + i] = (__bf16)(v16[i] * inv);
    }
    __syncthreads();

    // ---- phase 5: blk = P @ vals (M=k, N=d 5 tiles, K=c=64) + cs ----
    {
        const __bf16* pr = P + (w * 16 + l16) * 72 + quad * 8;
        bf16x8 pa0 = *(const bf16x8*)pr;
        bf16x8 pa1 = *(const bf16x8*)(pr + 32);
        const f32x4 z = {0.f, 0.f, 0.f, 0.f};
        float csr[4] = {0.f, 0.f, 0.f, 0.f};
        #pragma unroll
        for (int nt = 0; nt < 5; ++nt) {
            const __bf16* vb = valsT + (nt * 16 + l16) * 72 + quad * 8;
            f32x4 o = MFMA16(pa0, *(const bf16x8*)vb, z);
            o = MFMA16(pa1, *(const bf16x8*)(vb + 32), o);
            const int d = nt * 16 + l16;
            const bool valid = (d <= 64);
            const float cqd = valid ? cq[d] : 0.f;
            #pragma unroll
            for (int r = 0; r < 4; ++r) {
                const int k = w * 16 + quad * 4 + r;
                if (valid) {
                    blk_out[(((size_t)b * KQ + k) * NBLK + nb) * DDIM + d] =
                        (__bf16)o[r];
                    csr[r] += o[r] * cqd;     // guarded: no NaN from pad cols
                }
            }
        }
        #pragma unroll
        for (int r = 0; r < 4; ++r) {
            float v = csr[r];
            v += __shfl_xor(v, 1);
            v += __shfl_xor(v, 2);
            v += __shfl_xor(v, 4);
            v += __shfl_xor(v, 8);
            if (l16 == 0) cs_l[w * 16 + quad * 4 + r] = v;
        }
    }
    __syncthreads();
    if (tid < KQ)
        cs_out[((size_t)b * KQ + tid) * NBLK + nb] = cs_l[tid] * SCALE;
}

// ---------------------------------------------------------------------------
// Kernel 4: cross softmax over nb, weighted sum of blk, residual, LayerNorm.
// ---------------------------------------------------------------------------
__global__ __launch_bounds__(256) void k_cross(
    const __bf16* __restrict__ blk, const float* __restrict__ cs,
    const float* __restrict__ r, const float* __restrict__ gamma,
    const float* __restrict__ beta, float* __restrict__ out) {
    const int bk_ = blockIdx.x;
    const int b = bk_ >> 6;
    const int tid = threadIdx.x;
    const int w = tid >> 6, lane = tid & 63;

    __shared__ float ew[NBLK];
    __shared__ float red[4][DDIM];
    __shared__ float vv[DDIM];
    __shared__ float wredA[4];
    __shared__ float stats[2];

    const float v = cs[(size_t)bk_ * NBLK + tid];
    float m = v;
    for (int off = 32; off; off >>= 1) m = fmaxf(m, __shfl_down(m, off));
    if (lane == 0) wredA[w] = m;
    __syncthreads();
    m = fmaxf(fmaxf(wredA[0], wredA[1]), fmaxf(wredA[2], wredA[3]));
    const float e = __expf(v - m);
    ew[tid] = e;
    float s = e;
    for (int off = 32; off; off >>= 1) s += __shfl_down(s, off);
    __syncthreads();
    if (lane == 0) wredA[w] = s;
    __syncthreads();
    const float inv = 1.0f / (wredA[0] + wredA[1] + wredA[2] + wredA[3]);

    const __bf16* base = blk + (size_t)bk_ * NBLK * DDIM;
    float acc = 0.f, acce = 0.f;
    for (int i = 0; i < 64; ++i) {
        const int n = w + i * 4;
        const __bf16* row = base + n * DDIM;
        const float wgt = ew[n];
        acc  += wgt * (float)row[lane];
        acce += wgt * (float)row[64];
    }
    red[w][lane] = acc;
    if (lane == 0) red[w][64] = acce;
    __syncthreads();
    if (tid < DDIM) {
        vv[tid] = (red[0][tid] + red[1][tid] + red[2][tid] + red[3][tid]) * inv
                  + r[b * DDIM + tid];
    }
    __syncthreads();
    if (tid < 64) {
        float a  = vv[tid] + (tid == 0 ? vv[64] : 0.f);
        float sq = vv[tid] * vv[tid] + (tid == 0 ? vv[64] * vv[64] : 0.f);
        for (int off = 32; off; off >>= 1) {
            a  += __shfl_down(a, off);
            sq += __shfl_down(sq, off);
        }
        if (tid == 0) {
            const float mu  = a * (1.0f / DDIM);
            const float var = sq * (1.0f / DDIM) - mu * mu;
            stats[0] = mu;
            stats[1] = rsqrtf(var + 1e-5f);
        }
    }
    __syncthreads();
    if (tid < DDIM) {
        out[(size_t)bk_ * DDIM + tid] =
            (vv[tid] - stats[0]) * stats[1] * gamma[tid] + beta[tid];
    }
}

// ---------------------------------------------------------------------------
extern "C" void kernel_launch(void* const* d_in, const int* in_sizes, int n_in,
                              void* d_out, int out_size, void* d_ws, size_t ws_size,
                              hipStream_t stream) {
    const float* x    = (const float*)d_in[0];
    const float* Wq1  = (const float*)d_in[1];
    const float* bq1  = (const float*)d_in[2];
    const float* Wq2  = (const float*)d_in[3];
    const float* bq2  = (const float*)d_in[4];
    const float* Wk   = (const float*)d_in[5];
    const float* bk   = (const float*)d_in[6];
    const float* Wv   = (const float*)d_in[7];
    const float* bv   = (const float*)d_in[8];
    const float* cq   = (const float*)d_in[9];
    const float* pos  = (const float*)d_in[10];
    const float* Wr   = (const float*)d_in[11];
    const float* br   = (const float*)d_in[12];
    const float* gamma= (const float*)d_in[13];
    const float* beta = (const float*)d_in[14];
    float* out = (float*)d_out;

    // workspace layout (floats then 16B-aligned byte offsets)
    char* w8 = (char*)d_ws;
    float*  gavg = (float*)w8;                       // 2080 f
    float*  rres = gavg + 2080;                      // 2080 f
    float*  q64  = rres + 2080;                      // 2048 f
    float*  hbuf = q64 + 2048;                       // 2080 f
    float*  cs   = hbuf + 2080;                      // 524288 f, ends 532576 f
    __bf16* qbf  = (__bf16*)(w8 + 2130304);          // 131072 bf16
    __bf16* WkT  = (__bf16*)(w8 + 2392448);          // 5120 bf16
    __bf16* WvT  = (__bf16*)(w8 + 2402688);          // 5120 bf16
    __bf16* blk  = (__bf16*)(w8 + 2412928);          // 34078720 bf16

    hipMemsetAsync(gavg, 0, 2080 * sizeof(float), stream);
    k_prep<<<40, 256, 0, stream>>>(Wk, Wv, WkT, WvT);
    k_gavg<<<dim3(64, BATCH), 256, 0, stream>>>(x, gavg);
    k_qgen1<<<BATCH, 256, 0, stream>>>(gavg, Wq1, bq1, Wr, br, hbuf, rres);
    k_qgen2<<<dim3(17, BATCH), 256, 0, stream>>>(hbuf, Wq2, bq2, qbf, q64);
    k_attn<<<dim3(NBLK, BATCH), 256, 0, stream>>>(x, qbf, q64, WkT, WvT,
                                                  Wk, bk, Wv, bv, pos, cq,
                                                  blk, cs);
    k_cross<<<BATCH * KQ, 256, 0, stream>>>(blk, cs, rres, gamma, beta, out);
}

// Round 4
// 377.551 us; speedup vs baseline: 3.9406x; 1.1618x over previous
//
#include <hip/hip_runtime.h>
#include <hip/hip_bf16.h>

// Problem constants
#define BATCH 32
#define NSEQ  16384
#define DDIM  65
#define CHUNK 64
#define KQ    64
#define NBLK  256          // NSEQ / CHUNK
#define SCALE 0.12403473458920847f   // 65^-0.5

typedef __bf16 bf16x8 __attribute__((ext_vector_type(8)));
typedef float  f32x4  __attribute__((ext_vector_type(4)));
#define MFMA16(a, b, c) __builtin_amdgcn_mfma_f32_16x16x32_bf16(a, b, c, 0, 0, 0)

__device__ __forceinline__ float gelu_exact(float v) {
    return 0.5f * v * (1.0f + erff(v * 0.7071067811865476f));
}

// tanh-approx GELU: |err| <= ~2e-4, far below bf16 rounding of keys/vals.
__device__ __forceinline__ float gelu_tanh(float x) {
    float x2 = x * x;
    float t  = 0.7978845608028654f * x * fmaf(0.044715f, x2, 1.0f);
    float e  = __expf(2.0f * t);
    float th = 1.0f - 2.0f * __builtin_amdgcn_rcpf(e + 1.0f);
    return 0.5f * x * (1.0f + th);
}

// ---------------------------------------------------------------------------
// Kernel 0: transpose+pad Wk,Wv to bf16 WT[80][64]: WT[d][e] = W[e][d], rows
// 65..79 zero.
// ---------------------------------------------------------------------------
__global__ __launch_bounds__(256) void k_prep(const float* __restrict__ Wk,
                                              const float* __restrict__ Wv,
                                              __bf16* __restrict__ WkT,
                                              __bf16* __restrict__ WvT) {
    int i = blockIdx.x * 256 + threadIdx.x;     // 0 .. 2*80*64-1
    if (i >= 2 * 80 * 64) return;
    int m = i / 5120;
    int j = i - m * 5120;
    int d = j >> 6, e = j & 63;
    const float* W = m ? Wv : Wk;
    __bf16* T = m ? WvT : WkT;
    T[(size_t)d * 64 + e] = (d < DDIM) ? (__bf16)W[e * DDIM + d] : (__bf16)0.0f;
}

// ---------------------------------------------------------------------------
// Kernel 1: per-slice partial sums over N (no atomics).  grid (64, 32).
// partial[(b*64+s)*65 + d]
// ---------------------------------------------------------------------------
__global__ __launch_bounds__(256) void k_gavg(const float* __restrict__ x,
                                              float* __restrict__ partial) {
    const int s = blockIdx.x;
    const int b = blockIdx.y;
    const int tid = threadIdx.x;
    const int w = tid >> 6, lane = tid & 63;
    const float* xb = x + (size_t)b * NSEQ * DDIM;
    const int n0 = s * 256;
    float acc = 0.f, acce = 0.f;
    #pragma unroll 4
    for (int i = 0; i < 64; ++i) {
        const float* row = xb + (size_t)(n0 + w + i * 4) * DDIM;
        acc  += row[lane];
        acce += row[64];
    }
    __shared__ float part[4][DDIM];
    part[w][lane] = acc;
    if (lane == 0) part[w][64] = acce;
    __syncthreads();
    if (tid < DDIM) {
        partial[((size_t)b * 64 + s) * DDIM + tid] =
            part[0][tid] + part[1][tid] + part[2][tid] + part[3][tid];
    }
}

// ---------------------------------------------------------------------------
// Kernel 2a: reduce partials -> gavg; h = gelu(gavg@Wq1+bq1); r = gavg@Wr+br.
// grid 32.
// ---------------------------------------------------------------------------
__global__ __launch_bounds__(256) void k_qgen1(const float* __restrict__ partial,
    const float* __restrict__ Wq1, const float* __restrict__ bq1,
    const float* __restrict__ Wr,  const float* __restrict__ br,
    float* __restrict__ h_out, float* __restrict__ r_out) {
    const int b = blockIdx.x, tid = threadIdx.x;
    __shared__ float g[DDIM];
    if (tid < DDIM) {
        float a = 0.f;
        const float* p = partial + (size_t)b * 64 * DDIM + tid;
        #pragma unroll 8
        for (int s = 0; s < 64; ++s) a += p[s * DDIM];
        g[tid] = a * (1.0f / 16384.0f);
    }
    __syncthreads();
    if (tid < DDIM) {
        float a = bq1[tid];
        for (int e = 0; e < DDIM; ++e) a += g[e] * Wq1[e * DDIM + tid];
        h_out[b * DDIM + tid] = gelu_exact(a);
    } else if (tid >= 128 && tid < 128 + DDIM) {
        const int d = tid - 128;
        float a = br[d];
        for (int e = 0; e < DDIM; ++e) a += g[e] * Wr[e * DDIM + d];
        r_out[b * DDIM + d] = a;
    }
}

// ---------------------------------------------------------------------------
// Kernel 2b: q = (h@Wq2+bq2)*SCALE -> qbf [64][64] bf16 + q64 col.
// ---------------------------------------------------------------------------
__global__ __launch_bounds__(256) void k_qgen2(const float* __restrict__ h_in,
    const float* __restrict__ Wq2, const float* __restrict__ bq2,
    __bf16* __restrict__ qbf, float* __restrict__ q64) {
    const int b = blockIdx.y, tid = threadIdx.x;
    const int o = blockIdx.x * 256 + tid;
    __shared__ float h[DDIM];
    if (tid < DDIM) h[tid] = h_in[b * DDIM + tid];
    __syncthreads();
    if (o >= KQ * DDIM) return;
    float a = bq2[o];
    #pragma unroll 13
    for (int e = 0; e < DDIM; ++e) a += h[e] * Wq2[e * (KQ * DDIM) + o];
    a *= SCALE;
    const int k = o / DDIM, d = o - k * DDIM;
    if (d < 64) qbf[(size_t)b * 4096 + k * 64 + d] = (__bf16)a;
    else        q64[b * 64 + k] = a;
}

// ---------------------------------------------------------------------------
// Kernel 3 (MFMA): per (b, chunk).  In-register softmax; LDS 27.9 KB ->
// 5 blocks/CU.  D=65: MFMA over 64 + fp32 rank-1 fixup; d=64 output column
// computed from fp32 P during softmax.
// ---------------------------------------------------------------------------
__global__ __launch_bounds__(256, 5) void k_attn(const float* __restrict__ x,
    const __bf16* __restrict__ qbf, const float* __restrict__ q64,
    const __bf16* __restrict__ WkT, const __bf16* __restrict__ WvT,
    const float* __restrict__ Wk, const float* __restrict__ bkb,
    const float* __restrict__ Wv, const float* __restrict__ bvb,
    const float* __restrict__ pos, const float* __restrict__ cq,
    __bf16* __restrict__ blk_out, float* __restrict__ cs_out) {
    const int nb = blockIdx.x;
    const int b  = blockIdx.y;
    const int tid = threadIdx.x;
    const int lane = tid & 63, w = tid >> 6;
    const int l16 = lane & 15, quad = lane >> 4;

    __shared__ __align__(16) __bf16 xsP[64 * 72];    // x chunk, then P
    __shared__ __align__(16) __bf16 keys[64 * 72];   // [c][d], cols 0..64
    __shared__ __align__(16) __bf16 valsT[64 * 72];  // [d][c], d<64
    __shared__ float vals64[64];                     // vals[c][64] fp32
    __shared__ float xs64[64];                       // x[c][64]

    // ---- phase 1: stage x chunk (div-free, 4 threads per row) ----
    {
        const int c = tid >> 2, g = tid & 3;
        const float* xrow = x + ((size_t)b * NSEQ + (size_t)nb * CHUNK + c) * DDIM;
        __bf16* dst = xsP + c * 72;
        #pragma unroll
        for (int j = 0; j < 16; ++j)
            dst[g + 4 * j] = (__bf16)xrow[g + 4 * j];
        if (g == 0) xs64[c] = xrow[64];
    }
    __syncthreads();

    // ---- phase 2: keys/vals via MFMA (M=c, N=d 5 tiles, K=64) ----
    {
        const __bf16* arow = xsP + (w * 16 + l16) * 72 + quad * 8;
        bf16x8 a0 = *(const bf16x8*)arow;
        bf16x8 a1 = *(const bf16x8*)(arow + 32);
        f32x4 ak[5], av[5];
        const f32x4 z = {0.f, 0.f, 0.f, 0.f};
        #pragma unroll
        for (int nt = 0; nt < 5; ++nt) {
            const __bf16* bkr = WkT + (nt * 16 + l16) * 64 + quad * 8;
            const __bf16* bvr = WvT + (nt * 16 + l16) * 64 + quad * 8;
            ak[nt] = MFMA16(a0, *(const bf16x8*)bkr, z);
            ak[nt] = MFMA16(a1, *(const bf16x8*)(bkr + 32), ak[nt]);
            av[nt] = MFMA16(a0, *(const bf16x8*)bvr, z);
            av[nt] = MFMA16(a1, *(const bf16x8*)(bvr + 32), av[nt]);
        }
        float xe[4];
        #pragma unroll
        for (int r = 0; r < 4; ++r) xe[r] = xs64[w * 16 + quad * 4 + r];
        #pragma unroll
        for (int nt = 0; nt < 5; ++nt) {
            const int d = nt * 16 + l16;
            if (d <= 64) {
                const float wk64d = Wk[64 * DDIM + d];
                const float wv64d = Wv[64 * DDIM + d];
                const float bkd = bkb[d], bvd = bvb[d];
                #pragma unroll
                for (int r = 0; r < 4; ++r) {
                    const int c = w * 16 + quad * 4 + r;
                    const float pv = pos[c * DDIM + d];
                    const float kvv = gelu_tanh(ak[nt][r] + xe[r] * wk64d + bkd) + pv;
                    const float vvv = gelu_tanh(av[nt][r] + xe[r] * wv64d + bvd) + pv;
                    keys[c * 72 + d] = (__bf16)kvv;
                    if (d < 64) valsT[d * 72 + c] = (__bf16)vvv;
                    else        vals64[c] = vvv;
                }
            }
        }
    }
    __syncthreads();

    // ---- phase 3: S = q@keys^T + fixup, in-register softmax, P store,
    //      d=64 output column + its cs contribution ----
    float csr[4];
    {
        const __bf16* aq = qbf + (size_t)b * 4096 + (w * 16 + l16) * 64 + quad * 8;
        bf16x8 qa0 = *(const bf16x8*)aq;
        bf16x8 qa1 = *(const bf16x8*)(aq + 32);
        const f32x4 z = {0.f, 0.f, 0.f, 0.f};
        float st[4][4];                 // [nt][r]
        #pragma unroll
        for (int nt = 0; nt < 4; ++nt) {
            const __bf16* kb = keys + (nt * 16 + l16) * 72 + quad * 8;
            f32x4 sacc = MFMA16(qa0, *(const bf16x8*)kb, z);
            sacc = MFMA16(qa1, *(const bf16x8*)(kb + 32), sacc);
            const float k64c = (float)keys[(nt * 16 + l16) * 72 + 64];
            #pragma unroll
            for (int r = 0; r < 4; ++r) st[nt][r] = sacc[r] * SCALE + 0.f * k64c;
            // fixup folded below (needs q64k)
            #pragma unroll
            for (int r = 0; r < 4; ++r)
                st[nt][r] = sacc[r];    // raw; fixup+scale applied next
            // keep k64c for fixup
            #pragma unroll
            for (int r = 0; r < 4; ++r)
                st[nt][r] = fmaf(q64[b * 64 + w * 16 + quad * 4 + r], k64c,
                                 st[nt][r]) * SCALE;
        }
        // rowwise max over c (4 regs + 16-lane group)
        float mr[4], sum[4], inv[4];
        #pragma unroll
        for (int r = 0; r < 4; ++r) {
            float m = fmaxf(fmaxf(st[0][r], st[1][r]), fmaxf(st[2][r], st[3][r]));
            m = fmaxf(m, __shfl_xor(m, 1));
            m = fmaxf(m, __shfl_xor(m, 2));
            m = fmaxf(m, __shfl_xor(m, 4));
            m = fmaxf(m, __shfl_xor(m, 8));
            mr[r] = m;
            sum[r] = 0.f;
        }
        #pragma unroll
        for (int nt = 0; nt < 4; ++nt)
            #pragma unroll
            for (int r = 0; r < 4; ++r) {
                st[nt][r] = __expf(st[nt][r] - mr[r]);
                sum[r] += st[nt][r];
            }
        #pragma unroll
        for (int r = 0; r < 4; ++r) {
            float s = sum[r];
            s += __shfl_xor(s, 1);
            s += __shfl_xor(s, 2);
            s += __shfl_xor(s, 4);
            s += __shfl_xor(s, 8);
            inv[r] = __builtin_amdgcn_rcpf(s);
        }
        // store P (bf16) into xsP region (xs dead since phase-2 barrier)
        #pragma unroll
        for (int nt = 0; nt < 4; ++nt)
            #pragma unroll
            for (int r = 0; r < 4; ++r)
                xsP[(w * 16 + quad * 4 + r) * 72 + nt * 16 + l16] =
                    (__bf16)(st[nt][r] * inv[r]);
        // d=64 output column from fp32 P
        float v64l[4];
        #pragma unroll
        for (int nt = 0; nt < 4; ++nt) v64l[nt] = vals64[nt * 16 + l16];
        const float cq64 = cq[64];
        #pragma unroll
        for (int r = 0; r < 4; ++r) {
            float o = st[0][r] * v64l[0];
            o = fmaf(st[1][r], v64l[1], o);
            o = fmaf(st[2][r], v64l[2], o);
            o = fmaf(st[3][r], v64l[3], o);
            o += __shfl_xor(o, 1);
            o += __shfl_xor(o, 2);
            o += __shfl_xor(o, 4);
            o += __shfl_xor(o, 8);
            csr[r] = 0.f;
            if (l16 == 0) {
                const float o64 = o * inv[r];
                const int k = w * 16 + quad * 4 + r;
                blk_out[(((size_t)b * KQ + k) * NBLK + nb) * DDIM + 64] =
                    (__bf16)o64;
                csr[r] = o64 * cq64;
            }
        }
    }
    __syncthreads();

    // ---- phase 5: blk = P @ vals (M=k, N=d 4 tiles, K=64) + cs ----
    {
        const __bf16* pr = xsP + (w * 16 + l16) * 72 + quad * 8;
        bf16x8 pa0 = *(const bf16x8*)pr;
        bf16x8 pa1 = *(const bf16x8*)(pr + 32);
        const f32x4 z = {0.f, 0.f, 0.f, 0.f};
        #pragma unroll
        for (int nt = 0; nt < 4; ++nt) {
            const __bf16* vb = valsT + (nt * 16 + l16) * 72 + quad * 8;
            f32x4 o = MFMA16(pa0, *(const bf16x8*)vb, z);
            o = MFMA16(pa1, *(const bf16x8*)(vb + 32), o);
            const int d = nt * 16 + l16;
            const float cqd = cq[d];
            #pragma unroll
            for (int r = 0; r < 4; ++r) {
                const int k = w * 16 + quad * 4 + r;
                blk_out[(((size_t)b * KQ + k) * NBLK + nb) * DDIM + d] =
                    (__bf16)o[r];
                csr[r] = fmaf(o[r], cqd, csr[r]);
            }
        }
        #pragma unroll
        for (int r = 0; r < 4; ++r) {
            float v = csr[r];
            v += __shfl_xor(v, 1);
            v += __shfl_xor(v, 2);
            v += __shfl_xor(v, 4);
            v += __shfl_xor(v, 8);
            if (l16 == 0) {
                const int k = w * 16 + quad * 4 + r;
                cs_out[((size_t)b * KQ + k) * NBLK + nb] = v * SCALE;
            }
        }
    }
}

// ---------------------------------------------------------------------------
// Kernel 4: cross softmax over nb, weighted sum of blk, residual, LayerNorm.
// ---------------------------------------------------------------------------
__global__ __launch_bounds__(256) void k_cross(
    const __bf16* __restrict__ blk, const float* __restrict__ cs,
    const float* __restrict__ r, const float* __restrict__ gamma,
    const float* __restrict__ beta, float* __restrict__ out) {
    const int bk_ = blockIdx.x;
    const int b = bk_ >> 6;
    const int tid = threadIdx.x;
    const int w = tid >> 6, lane = tid & 63;

    __shared__ float ew[NBLK];
    __shared__ float red[4][DDIM];
    __shared__ float vv[DDIM];
    __shared__ float wredA[4];
    __shared__ float stats[2];

    const float v = cs[(size_t)bk_ * NBLK + tid];
    float m = v;
    for (int off = 32; off; off >>= 1) m = fmaxf(m, __shfl_down(m, off));
    if (lane == 0) wredA[w] = m;
    __syncthreads();
    m = fmaxf(fmaxf(wredA[0], wredA[1]), fmaxf(wredA[2], wredA[3]));
    const float e = __expf(v - m);
    ew[tid] = e;
    float s = e;
    for (int off = 32; off; off >>= 1) s += __shfl_down(s, off);
    __syncthreads();
    if (lane == 0) wredA[w] = s;
    __syncthreads();
    const float inv = 1.0f / (wredA[0] + wredA[1] + wredA[2] + wredA[3]);

    const __bf16* base = blk + (size_t)bk_ * NBLK * DDIM;
    float acc = 0.f, acce = 0.f;
    #pragma unroll 4
    for (int i = 0; i < 64; ++i) {
        const int n = w + i * 4;
        const __bf16* row = base + n * DDIM;
        const float wgt = ew[n];
        acc  += wgt * (float)row[lane];
        acce += wgt * (float)row[64];
    }
    red[w][lane] = acc;
    if (lane == 0) red[w][64] = acce;
    __syncthreads();
    if (tid < DDIM) {
        vv[tid] = (red[0][tid] + red[1][tid] + red[2][tid] + red[3][tid]) * inv
                  + r[b * DDIM + tid];
    }
    __syncthreads();
    if (tid < 64) {
        float a  = vv[tid] + (tid == 0 ? vv[64] : 0.f);
        float sq = vv[tid] * vv[tid] + (tid == 0 ? vv[64] * vv[64] : 0.f);
        for (int off = 32; off; off >>= 1) {
            a  += __shfl_down(a, off);
            sq += __shfl_down(sq, off);
        }
        if (tid == 0) {
            const float mu  = a * (1.0f / DDIM);
            const float var = sq * (1.0f / DDIM) - mu * mu;
            stats[0] = mu;
            stats[1] = rsqrtf(var + 1e-5f);
        }
    }
    __syncthreads();
    if (tid < DDIM) {
        out[(size_t)bk_ * DDIM + tid] =
            (vv[tid] - stats[0]) * stats[1] * gamma[tid] + beta[tid];
    }
}

// ---------------------------------------------------------------------------
extern "C" void kernel_launch(void* const* d_in, const int* in_sizes, int n_in,
                              void* d_out, int out_size, void* d_ws, size_t ws_size,
                              hipStream_t stream) {
    const float* x    = (const float*)d_in[0];
    const float* Wq1  = (const float*)d_in[1];
    const float* bq1  = (const float*)d_in[2];
    const float* Wq2  = (const float*)d_in[3];
    const float* bq2  = (const float*)d_in[4];
    const float* Wk   = (const float*)d_in[5];
    const float* bk   = (const float*)d_in[6];
    const float* Wv   = (const float*)d_in[7];
    const float* bv   = (const float*)d_in[8];
    const float* cq   = (const float*)d_in[9];
    const float* pos  = (const float*)d_in[10];
    const float* Wr   = (const float*)d_in[11];
    const float* br   = (const float*)d_in[12];
    const float* gamma= (const float*)d_in[13];
    const float* beta = (const float*)d_in[14];
    float* out = (float*)d_out;

    // workspace layout (byte offsets, all 16B-aligned)
    char* w8 = (char*)d_ws;
    float*  partial = (float*)w8;                    // 133120 f  @0
    float*  rres    = (float*)(w8 + 532480);         // 2080 f
    float*  q64     = (float*)(w8 + 540800);         // 2048 f
    float*  hbuf    = (float*)(w8 + 548992);         // 2080 f
    float*  cs      = (float*)(w8 + 557312);         // 524288 f
    __bf16* qbf     = (__bf16*)(w8 + 2654464);       // 131072 bf16
    __bf16* WkT     = (__bf16*)(w8 + 2916608);       // 5120 bf16
    __bf16* WvT     = (__bf16*)(w8 + 2926848);       // 5120 bf16
    __bf16* blk     = (__bf16*)(w8 + 2937088);       // 34078720 bf16

    k_prep<<<40, 256, 0, stream>>>(Wk, Wv, WkT, WvT);
    k_gavg<<<dim3(64, BATCH), 256, 0, stream>>>(x, partial);
    k_qgen1<<<BATCH, 256, 0, stream>>>(partial, Wq1, bq1, Wr, br, hbuf, rres);
    k_qgen2<<<dim3(17, BATCH), 256, 0, stream>>>(hbuf, Wq2, bq2, qbf, q64);
    k_attn<<<dim3(NBLK, BATCH), 256, 0, stream>>>(x, qbf, q64, WkT, WvT,
                                                  Wk, bk, Wv, bv, pos, cq,
                                                  blk, cs);
    k_cross<<<BATCH * KQ, 256, 0, stream>>>(blk, cs, rres, gamma, beta, out);
}